// Round 7
// baseline (1175.830 us; speedup 1.0000x reference)
//
#include <hip/hip_runtime.h>
#include <hip/hip_bf16.h>

// VQ quantize. input [8,64,64,256] f32 -> flatten [M=32768, K=256]
// embed [K=256, N=4096] f32. Outputs in d_out (f32):
//   quantize [8388608], diff [1], embed_ind [32768] (as float)
//
// bf16-MFMA GEMM (256x256 tile, single-buffered, PROVEN r5) stores top-2
// approx keys per (row, 128-code group). Rescore: rigorous threshold window
// -> per-lane serial exact f32 chains (bit-matching r1/r2/r5) -> argmin,
// gather, STE, diff. This round: rescore dot is software-pipelined
// (2-deep double-buffered loads, same fmaf order) + 1 row per wave.

#define M_ROWS 32768
#define K_DIM 256
#define N_CODES 4096

typedef __attribute__((ext_vector_type(8))) short short8v;
typedef __attribute__((ext_vector_type(4))) float f32x4;

__device__ inline unsigned long long packKey(float d, int idx) {
    unsigned u = __float_as_uint(d);
    u = (u & 0x80000000u) ? ~u : (u | 0x80000000u);
    return ((unsigned long long)u << 32) | (unsigned)idx;
}
__device__ inline float unpackDist(unsigned long long k) {
    unsigned u = (unsigned)(k >> 32);
    u = (u & 0x80000000u) ? (u & 0x7FFFFFFFu) : ~u;
    return __uint_as_float(u);
}
__device__ inline unsigned short f2bf(float x) {
    __hip_bfloat16 h = __float2bfloat16(x);
    return *reinterpret_cast<unsigned short*>(&h);
}
__device__ inline unsigned long long u64min(unsigned long long a, unsigned long long b) {
    return a < b ? a : b;
}
__device__ inline unsigned long long u64max(unsigned long long a, unsigned long long b) {
    return a > b ? a : b;
}

// Bit-identical to the proven serial chain (ascending k, fmaf x,y,z,w) but
// with 2-deep double-buffered load staging so only ONE memory latency is
// exposed instead of 64. All array indices are compile-time (rule #20).
__device__ inline float serial_dot(const float4* __restrict__ fr,
                                   const float4* __restrict__ er) {
    float4 fa0[4], ea0[4], fa1[4], ea1[4];
#pragma unroll
    for (int j = 0; j < 4; ++j) { fa0[j] = fr[j]; ea0[j] = er[j]; }
    float ex = 0.f;
#pragma unroll
    for (int b = 0; b < 16; b += 2) {
        if (b + 1 < 16) {
#pragma unroll
            for (int j = 0; j < 4; ++j) {
                fa1[j] = fr[(b + 1) * 4 + j];
                ea1[j] = er[(b + 1) * 4 + j];
            }
        }
#pragma unroll
        for (int j = 0; j < 4; ++j) {
            ex = fmaf(fa0[j].x, ea0[j].x, ex); ex = fmaf(fa0[j].y, ea0[j].y, ex);
            ex = fmaf(fa0[j].z, ea0[j].z, ex); ex = fmaf(fa0[j].w, ea0[j].w, ex);
        }
        if (b + 2 < 16) {
#pragma unroll
            for (int j = 0; j < 4; ++j) {
                fa0[j] = fr[(b + 2) * 4 + j];
                ea0[j] = er[(b + 2) * 4 + j];
            }
        }
#pragma unroll
        for (int j = 0; j < 4; ++j) {
            ex = fmaf(fa1[j].x, ea1[j].x, ex); ex = fmaf(fa1[j].y, ea1[j].y, ex);
            ex = fmaf(fa1[j].z, ea1[j].z, ex); ex = fmaf(fa1[j].w, ea1[j].w, ex);
        }
    }
    return ex;
}

// ---------------- transpose E -> Et [N][K] f32 + Ethi [N][K] bf16 ----------
__global__ void transpose_kernel(const float* __restrict__ E,
                                 float* __restrict__ Et,
                                 unsigned short* __restrict__ Ethi) {
    __shared__ float tile[64][65];
    const int kb = blockIdx.x & 3;
    const int jb = blockIdx.x >> 2;
    const int t = threadIdx.x;
#pragma unroll
    for (int it = 0; it < 16; ++it) {
        int linear = it * 256 + t;
        int kk = linear >> 6, jj = linear & 63;
        tile[kk][jj] = E[(size_t)(kb * 64 + kk) * N_CODES + jb * 64 + jj];
    }
    __syncthreads();
#pragma unroll
    for (int it = 0; it < 16; ++it) {
        int linear = it * 256 + t;
        int jj = linear >> 6, kk = linear & 63;
        float v = tile[kk][jj];
        size_t o = (size_t)(jb * 64 + jj) * K_DIM + kb * 64 + kk;
        Et[o] = v;
        Ethi[o] = f2bf(v);
    }
}

// ---------------- norms from Et + max norm ----------------
__global__ void nrm_et_kernel(const float* __restrict__ Et,
                              float* __restrict__ nrm,
                              float* __restrict__ maxnrm) {
    const int l = threadIdx.x & 63;
    const int j = blockIdx.x * 4 + (threadIdx.x >> 6);
    float4 v = *(const float4*)&Et[(size_t)j * K_DIM + l * 4];
    float s = v.x * v.x;
    s = fmaf(v.y, v.y, s); s = fmaf(v.z, v.z, s); s = fmaf(v.w, v.w, s);
#pragma unroll
    for (int sh = 32; sh >= 1; sh >>= 1) s += __shfl_xor(s, sh, 64);
    if (l == 0) {
        nrm[j] = s;
        atomicMax((int*)maxnrm, __float_as_int(s));  // positive floats
    }
}

// ---------------- bf16 MFMA GEMM, 256x256 tile, top-2 epilogue -------------
// PROVEN round 5 — unchanged.
__global__ __launch_bounds__(512) void gemm_top2_kernel(
    const float* __restrict__ F,              // [M][K] f32
    const unsigned short* __restrict__ Ethi,  // [N][K] bf16
    const float* __restrict__ nrm,            // [N]
    unsigned long long* __restrict__ keys2)   // [M][32][2]
{
    __shared__ unsigned short sA[256 * 64];
    __shared__ unsigned short sB[256 * 64];
    const int tid = threadIdx.x;
    const int l = tid & 63;
    const int wid = tid >> 6;
    const int tile = (blockIdx.x & 7) * 256 + (blockIdx.x >> 3);
    const int by = tile >> 4, bx = tile & 15;
    const int bm0 = by * 256, bn0 = bx * 256;
    const int wm = wid >> 1, wn = wid & 1;

    f32x4 acc[4][8];
#pragma unroll
    for (int mi = 0; mi < 4; ++mi)
#pragma unroll
        for (int ni = 0; ni < 8; ++ni) acc[mi][ni] = (f32x4){0.f, 0.f, 0.f, 0.f};

    const float* aSrc = F + (size_t)(bm0 + wid * 32 + (l >> 1)) * K_DIM + (l & 1) * 32;
    const int arow = wid * 32 + (l >> 1);

#pragma unroll
    for (int kt = 0; kt < 4; ++kt) {
        float4 areg[8];
#pragma unroll
        for (int i = 0; i < 8; ++i)
            areg[i] = *(const float4*)(aSrc + kt * 64 + i * 4);

        if (kt > 0) __syncthreads();

#pragma unroll
        for (int j = 0; j < 4; ++j) {
            short8v hv;
            hv[0] = (short)f2bf(areg[2 * j].x);     hv[1] = (short)f2bf(areg[2 * j].y);
            hv[2] = (short)f2bf(areg[2 * j].z);     hv[3] = (short)f2bf(areg[2 * j].w);
            hv[4] = (short)f2bf(areg[2 * j + 1].x); hv[5] = (short)f2bf(areg[2 * j + 1].y);
            hv[6] = (short)f2bf(areg[2 * j + 1].z); hv[7] = (short)f2bf(areg[2 * j + 1].w);
            int c = (l & 1) * 4 + j, phys = c ^ (arow & 7);
            *(short8v*)&sA[arow * 64 + phys * 8] = hv;
        }
#pragma unroll
        for (int i = 0; i < 4; ++i) {
            int q = wid * 4 + i;
            const unsigned short* src = Ethi +
                (size_t)(bn0 + q * 8 + (l >> 3)) * K_DIM + kt * 64 +
                ((l & 7) ^ (l >> 3)) * 8;
            __builtin_amdgcn_global_load_lds(
                (const __attribute__((address_space(1))) unsigned int*)src,
                (__attribute__((address_space(3))) unsigned int*)&sB[q * 512],
                16, 0, 0);
        }
        __syncthreads();

#pragma unroll
        for (int s = 0; s < 2; ++s) {
            const int ch = s * 4 + (l >> 4);
            short8v af[4], bfv[8];
#pragma unroll
            for (int mi = 0; mi < 4; ++mi) {
                int r = wm * 64 + mi * 16 + (l & 15);
                af[mi] = *(const short8v*)&sA[r * 64 + (ch ^ (r & 7)) * 8];
            }
#pragma unroll
            for (int ni = 0; ni < 8; ++ni) {
                int c = wn * 128 + ni * 16 + (l & 15);
                bfv[ni] = *(const short8v*)&sB[c * 64 + (ch ^ (c & 7)) * 8];
            }
#pragma unroll
            for (int mi = 0; mi < 4; ++mi)
#pragma unroll
                for (int ni = 0; ni < 8; ++ni)
                    acc[mi][ni] = __builtin_amdgcn_mfma_f32_16x16x32_bf16(
                        af[mi], bfv[ni], acc[mi][ni], 0, 0, 0);
        }
    }

    float nv[8];
#pragma unroll
    for (int ni = 0; ni < 8; ++ni)
        nv[ni] = nrm[bn0 + wn * 128 + ni * 16 + (l & 15)];

#pragma unroll
    for (int mi = 0; mi < 4; ++mi)
#pragma unroll
        for (int rr = 0; rr < 4; ++rr) {
            unsigned long long k1 = ~0ull, k2 = ~0ull;
#pragma unroll
            for (int ni = 0; ni < 8; ++ni) {
                float d = fmaf(-2.f, acc[mi][ni][rr], nv[ni]);
                unsigned long long kk =
                    packKey(d, bn0 + wn * 128 + ni * 16 + (l & 15));
                if (kk < k1) { k2 = k1; k1 = kk; }
                else if (kk < k2) { k2 = kk; }
            }
#pragma unroll
            for (int st = 1; st < 16; st <<= 1) {
                unsigned long long o1 = __shfl_xor(k1, st, 64);
                unsigned long long o2 = __shfl_xor(k2, st, 64);
                unsigned long long hi = u64max(k1, o1);
                k1 = u64min(k1, o1);
                k2 = u64min(u64min(k2, o2), hi);
            }
            if ((l & 15) == 0) {
                int row = bm0 + wm * 64 + mi * 16 + (l >> 4) * 4 + rr;
                int g = bx * 2 + wn;
                keys2[(size_t)row * 64 + g * 2]     = k1;
                keys2[(size_t)row * 64 + g * 2 + 1] = k2;
            }
        }
}

// ---------------- rescore: 1 row per wave, pipelined serial chains ---------
// Same decision procedure as r5 (proven): window from top-2 keys, per-lane
// serial exact dots for in-window slots, full-group scan when a group's
// rank-2 is in-window, u64min winner, gather + STE + diff + index.
__global__ __launch_bounds__(256) void rescore_kernel(
    const float* __restrict__ F,
    const float* __restrict__ Et,
    const float* __restrict__ nrm,
    const float* __restrict__ maxnrm,
    const unsigned long long* __restrict__ keys2,
    float* __restrict__ q_out,
    float* __restrict__ diff_out,
    float* __restrict__ ind_out)
{
    __shared__ float wpart[4];
    const int l = threadIdx.x & 63;
    const int wid = threadIdx.x >> 6;
    const float mxn = maxnrm[0];
    const int row = blockIdx.x * 4 + wid;   // 8192 blocks * 4 waves = 32768

    const unsigned long long* slots = keys2 + (size_t)row * 64;
    const float4* fr = (const float4*)&F[(size_t)row * K_DIM];

    unsigned long long k = slots[l];
    float4 x4 = fr[l];
    float dk = unpackDist(k);
    float m = dk;
#pragma unroll
    for (int s = 1; s < 64; s <<= 1) m = fminf(m, __shfl_xor(m, s, 64));
    float nx = x4.x * x4.x;
    nx = fmaf(x4.y, x4.y, nx); nx = fmaf(x4.z, x4.z, nx); nx = fmaf(x4.w, x4.w, nx);
#pragma unroll
    for (int s = 1; s < 64; s <<= 1) nx += __shfl_xor(nx, s, 64);
    // window: rigorous 2*Delta = 0.03125*||x||*maxE; use 1.6x + slack
    const float thr = m + 0.05f * sqrtf(nx * mxn) + 0.25f;

    const unsigned long long cm = __ballot(dk <= thr);
    unsigned long long bestk = ~0ull;

    // lane l takes the l-th set bit of cm: pipelined serial exact rescore
    {
        unsigned long long t = cm;
        for (int i = 0; i < l && t; ++i) t &= t - 1;
        if (t) {
            int b = __ffsll(t) - 1;
            int c = (int)(slots[b] & 0xffffffffull);
            float ex = serial_dot(fr, (const float4*)&Et[(size_t)c * K_DIM]);
            bestk = packKey(fmaf(-2.f, ex, nrm[c]), c);
        }
    }
    // fallback: groups whose stored rank-2 is within thr -> scan all 128
    unsigned long long fg = cm & 0xAAAAAAAAAAAAAAAAull;
    while (fg) {
        int b = __ffsll(fg) - 1;
        fg &= fg - 1;
        int g = b >> 1;
#pragma unroll
        for (int h = 0; h < 2; ++h) {
            int c = g * 128 + h * 64 + l;
            float ex = serial_dot(fr, (const float4*)&Et[(size_t)c * K_DIM]);
            bestk = u64min(bestk, packKey(fmaf(-2.f, ex, nrm[c]), c));
        }
    }
#pragma unroll
    for (int s = 1; s < 64; s <<= 1)
        bestk = u64min(bestk, __shfl_xor(bestk, s, 64));

    const unsigned cstar = (unsigned)(bestk & 0xffffffffull);
    float4 e4 = *(const float4*)&Et[(size_t)cstar * K_DIM + l * 4];
    float d0 = e4.x - x4.x, d1 = e4.y - x4.y, d2 = e4.z - x4.z, d3 = e4.w - x4.w;
    float4 o = {x4.x + d0, x4.y + d1, x4.z + d2, x4.w + d3};
    *(float4*)&q_out[(size_t)row * K_DIM + l * 4] = o;
    float ldiff = 0.f;
    ldiff = fmaf(d0, d0, ldiff); ldiff = fmaf(d1, d1, ldiff);
    ldiff = fmaf(d2, d2, ldiff); ldiff = fmaf(d3, d3, ldiff);
    if (l == 0) ind_out[row] = (float)cstar;

#pragma unroll
    for (int s = 1; s < 64; s <<= 1) ldiff += __shfl_xor(ldiff, s, 64);
    if (l == 0) wpart[wid] = ldiff;
    __syncthreads();
    if (threadIdx.x == 0) {
        float t = 0.f;
#pragma unroll
        for (int i = 0; i < 4; ++i) t += wpart[i];
        atomicAdd(diff_out, t * (1.0f / ((float)M_ROWS * (float)K_DIM)));
    }
}

// ======================= LEGACY f32 fallback (round-1, proven) ==============
__global__ void norms_kernel(const float* __restrict__ E, float* __restrict__ norms) {
    int j = blockIdx.x * blockDim.x + threadIdx.x;
    if (j >= N_CODES) return;
    float s = 0.f;
    for (int d = 0; d < K_DIM; ++d) {
        float v = E[(size_t)d * N_CODES + j];
        s = fmaf(v, v, s);
    }
    norms[j] = s;
}

__global__ __launch_bounds__(256, 2) void gemm_argmin_kernel(
    const float* __restrict__ F, const float* __restrict__ E,
    const float* __restrict__ norms, unsigned long long* __restrict__ keys) {
    __shared__ float As[32][132];
    __shared__ float Bs[32][132];
    const int bx = blockIdx.x & 31, by = blockIdx.x >> 5;
    const int bm0 = by * 128, bn0 = bx * 128;
    const int tid = threadIdx.x;
    const int tx = tid & 15, ty = tid >> 4;
    float acc[8][8];
#pragma unroll
    for (int i = 0; i < 8; ++i)
#pragma unroll
        for (int j = 0; j < 8; ++j) acc[i][j] = 0.f;
    for (int kc = 0; kc < K_DIM; kc += 32) {
        float4 a_reg[4], b_reg[4];
#pragma unroll
        for (int i = 0; i < 4; ++i) {
            int idx = tid + i * 256;
            int m = idx >> 3, k4 = idx & 7;
            a_reg[i] = *(const float4*)&F[(size_t)(bm0 + m) * K_DIM + kc + k4 * 4];
            int kk = idx >> 5, n4 = idx & 31;
            b_reg[i] = *(const float4*)&E[(size_t)(kc + kk) * N_CODES + bn0 + n4 * 4];
        }
        __syncthreads();
#pragma unroll
        for (int i = 0; i < 4; ++i) {
            int idx = tid + i * 256;
            int m = idx >> 3, k4 = idx & 7;
            As[k4 * 4 + 0][m] = a_reg[i].x; As[k4 * 4 + 1][m] = a_reg[i].y;
            As[k4 * 4 + 2][m] = a_reg[i].z; As[k4 * 4 + 3][m] = a_reg[i].w;
            int kk = idx >> 5, n4 = idx & 31;
            *(float4*)&Bs[kk][n4 * 4] = b_reg[i];
        }
        __syncthreads();
#pragma unroll
        for (int k = 0; k < 32; ++k) {
            float a[8], b[8];
            *(float4*)&a[0] = *(const float4*)&As[k][ty * 8];
            *(float4*)&a[4] = *(const float4*)&As[k][ty * 8 + 4];
            *(float4*)&b[0] = *(const float4*)&Bs[k][tx * 8];
            *(float4*)&b[4] = *(const float4*)&Bs[k][tx * 8 + 4];
#pragma unroll
            for (int i = 0; i < 8; ++i)
#pragma unroll
                for (int j = 0; j < 8; ++j) acc[i][j] = fmaf(a[i], b[j], acc[i][j]);
        }
    }
    float nrm8[8];
#pragma unroll
    for (int j = 0; j < 8; ++j) nrm8[j] = norms[bn0 + tx * 8 + j];
#pragma unroll
    for (int i = 0; i < 8; ++i) {
        float best = INFINITY; int bestj = 0;
#pragma unroll
        for (int j = 0; j < 8; ++j) {
            float d = fmaf(-2.f, acc[i][j], nrm8[j]);
            if (d < best) { best = d; bestj = bn0 + tx * 8 + j; }
        }
        unsigned long long key = packKey(best, bestj);
#pragma unroll
        for (int s = 1; s < 16; s <<= 1) {
            unsigned long long o = __shfl_xor(key, s, 64);
            if (o < key) key = o;
        }
        if (tx == 0) atomicMin(&keys[bm0 + ty * 8 + i], key);
    }
}

__global__ void gather_legacy_kernel(
    const float* __restrict__ F, const float* __restrict__ E,
    const unsigned long long* __restrict__ keys,
    float* __restrict__ q_out, float* __restrict__ diff_out,
    float* __restrict__ ind_out) {
    const int lane = threadIdx.x & 63;
    const int wave = (blockIdx.x * (blockDim.x >> 6)) + (threadIdx.x >> 6);
    const int nwaves = gridDim.x * (blockDim.x >> 6);
    float dsum = 0.f;
    for (int row = wave; row < M_ROWS; row += nwaves) {
        int ind = (int)(keys[row] & 0xFFFFFFFFull);
        if (lane == 0) ind_out[row] = (float)ind;
#pragma unroll
        for (int t = 0; t < 4; ++t) {
            int d = lane + t * 64;
            float x = F[(size_t)row * K_DIM + d];
            float q = E[(size_t)d * N_CODES + ind];
            float delta = q - x;
            q_out[(size_t)row * K_DIM + d] = x + delta;
            dsum = fmaf(delta, delta, dsum);
        }
    }
#pragma unroll
    for (int s = 32; s >= 1; s >>= 1) dsum += __shfl_xor(dsum, s, 64);
    if (lane == 0)
        atomicAdd(diff_out, dsum * (1.0f / ((float)M_ROWS * (float)K_DIM)));
}

// ============================== launch ==============================
extern "C" void kernel_launch(void* const* d_in, const int* in_sizes, int n_in,
                              void* d_out, int out_size, void* d_ws, size_t ws_size,
                              hipStream_t stream) {
    const float* F = (const float*)d_in[0];
    const float* E = (const float*)d_in[1];

    float* q_out = (float*)d_out;
    float* diff_out = q_out + (size_t)M_ROWS * K_DIM;
    float* ind_out = diff_out + 1;

    const size_t off_nrm  = 0;                       // 16 KB
    const size_t off_mx   = 16384;                   // 4 B
    const size_t off_Et   = 32768;                   // 4 MB
    const size_t off_Ethi = off_Et + (size_t)N_CODES * K_DIM * 4;    // 2 MB
    const size_t off_k2   = off_Ethi + (size_t)N_CODES * K_DIM * 2;  // 16 MB
    const size_t NEED     = off_k2 + (size_t)M_ROWS * 64 * 8;

    if (ws_size >= NEED) {
        float* nrm = (float*)((char*)d_ws + off_nrm);
        float* maxnrm = (float*)((char*)d_ws + off_mx);
        float* Et = (float*)((char*)d_ws + off_Et);
        unsigned short* Ethi = (unsigned short*)((char*)d_ws + off_Ethi);
        unsigned long long* keys2 = (unsigned long long*)((char*)d_ws + off_k2);

        hipMemsetAsync(maxnrm, 0, 4, stream);
        hipMemsetAsync(diff_out, 0, 4, stream);

        transpose_kernel<<<256, 256, 0, stream>>>(E, Et, Ethi);
        nrm_et_kernel<<<1024, 256, 0, stream>>>(Et, nrm, maxnrm);
        gemm_top2_kernel<<<2048, 512, 0, stream>>>(F, Ethi, nrm, keys2);
        rescore_kernel<<<8192, 256, 0, stream>>>(F, Et, nrm, maxnrm, keys2,
                                                 q_out, diff_out, ind_out);
    } else {
        float* norms = (float*)d_ws;
        unsigned long long* keys = (unsigned long long*)((char*)d_ws + 16384);
        hipMemsetAsync(keys, 0xFF, (size_t)M_ROWS * 8, stream);
        hipMemsetAsync(diff_out, 0, 4, stream);
        norms_kernel<<<N_CODES / 256, 256, 0, stream>>>(E, norms);
        gemm_argmin_kernel<<<(M_ROWS / 128) * (N_CODES / 128), 256, 0, stream>>>(F, E, norms, keys);
        gather_legacy_kernel<<<1024, 256, 0, stream>>>(F, E, keys, q_out, diff_out, ind_out);
    }
}

// Round 9
// 933.781 us; speedup vs baseline: 1.2592x; 1.2592x over previous
//
#include <hip/hip_runtime.h>
#include <hip/hip_bf16.h>

// VQ quantize. input [8,64,64,256] f32 -> flatten [M=32768, K=256]
// embed [K=256, N=4096] f32. Outputs in d_out (f32):
//   quantize [8388608], diff [1], embed_ind [32768] (as float)
//
// bf16-MFMA GEMM (256x256 tile, single-buffered, PROVEN r5) stores top-2
// approx keys per (row, 128-code group). Rescore (r9): threshold window ->
// LDS-staged candidates -> per-lane SERIAL ascending-k fmaf chains
// (bit-identical to r1/r2/r5/r7 -- tree-sum orders FAIL on this dataset,
// r3/r8 both absmax 1588) -> u64min argmin, gather, STE, diff.

#define M_ROWS 32768
#define K_DIM 256
#define N_CODES 4096

typedef __attribute__((ext_vector_type(8))) short short8v;
typedef __attribute__((ext_vector_type(4))) float f32x4;

__device__ inline unsigned long long packKey(float d, int idx) {
    unsigned u = __float_as_uint(d);
    u = (u & 0x80000000u) ? ~u : (u | 0x80000000u);
    return ((unsigned long long)u << 32) | (unsigned)idx;
}
__device__ inline float unpackDist(unsigned long long k) {
    unsigned u = (unsigned)(k >> 32);
    u = (u & 0x80000000u) ? (u & 0x7FFFFFFFu) : ~u;
    return __uint_as_float(u);
}
__device__ inline unsigned short f2bf(float x) {
    __hip_bfloat16 h = __float2bfloat16(x);
    return *reinterpret_cast<unsigned short*>(&h);
}
__device__ inline unsigned long long u64min(unsigned long long a, unsigned long long b) {
    return a < b ? a : b;
}
__device__ inline unsigned long long u64max(unsigned long long a, unsigned long long b) {
    return a > b ? a : b;
}

// The PROVEN serial chain (ascending k, fmaf x,y,z,w) reading from LDS.
// Values bit-identical to the global rows they were staged from.
__device__ inline float serial_dot_lds(const float* __restrict__ fp,
                                       const float* __restrict__ cp) {
    float ex = 0.f;
    for (int k4 = 0; k4 < 64; ++k4) {
        float4 a = *(const float4*)&fp[k4 * 4];
        float4 b = *(const float4*)&cp[k4 * 4];
        ex = fmaf(a.x, b.x, ex); ex = fmaf(a.y, b.y, ex);
        ex = fmaf(a.z, b.z, ex); ex = fmaf(a.w, b.w, ex);
    }
    return ex;
}

// ---------------- transpose E -> Et [N][K] f32 + Ethi [N][K] bf16 ----------
__global__ void transpose_kernel(const float* __restrict__ E,
                                 float* __restrict__ Et,
                                 unsigned short* __restrict__ Ethi) {
    __shared__ float tile[64][65];
    const int kb = blockIdx.x & 3;
    const int jb = blockIdx.x >> 2;
    const int t = threadIdx.x;
#pragma unroll
    for (int it = 0; it < 16; ++it) {
        int linear = it * 256 + t;
        int kk = linear >> 6, jj = linear & 63;
        tile[kk][jj] = E[(size_t)(kb * 64 + kk) * N_CODES + jb * 64 + jj];
    }
    __syncthreads();
#pragma unroll
    for (int it = 0; it < 16; ++it) {
        int linear = it * 256 + t;
        int jj = linear >> 6, kk = linear & 63;
        float v = tile[kk][jj];
        size_t o = (size_t)(jb * 64 + jj) * K_DIM + kb * 64 + kk;
        Et[o] = v;
        Ethi[o] = f2bf(v);
    }
}

// ---------------- norms from Et + max norm ----------------
__global__ void nrm_et_kernel(const float* __restrict__ Et,
                              float* __restrict__ nrm,
                              float* __restrict__ maxnrm) {
    const int l = threadIdx.x & 63;
    const int j = blockIdx.x * 4 + (threadIdx.x >> 6);
    float4 v = *(const float4*)&Et[(size_t)j * K_DIM + l * 4];
    float s = v.x * v.x;
    s = fmaf(v.y, v.y, s); s = fmaf(v.z, v.z, s); s = fmaf(v.w, v.w, s);
#pragma unroll
    for (int sh = 32; sh >= 1; sh >>= 1) s += __shfl_xor(s, sh, 64);
    if (l == 0) {
        nrm[j] = s;
        atomicMax((int*)maxnrm, __float_as_int(s));  // positive floats
    }
}

// ---------------- bf16 MFMA GEMM, 256x256 tile, top-2 epilogue -------------
// PROVEN round 5 — unchanged.
__global__ __launch_bounds__(512) void gemm_top2_kernel(
    const float* __restrict__ F,              // [M][K] f32
    const unsigned short* __restrict__ Ethi,  // [N][K] bf16
    const float* __restrict__ nrm,            // [N]
    unsigned long long* __restrict__ keys2)   // [M][32][2]
{
    __shared__ unsigned short sA[256 * 64];
    __shared__ unsigned short sB[256 * 64];
    const int tid = threadIdx.x;
    const int l = tid & 63;
    const int wid = tid >> 6;
    const int tile = (blockIdx.x & 7) * 256 + (blockIdx.x >> 3);
    const int by = tile >> 4, bx = tile & 15;
    const int bm0 = by * 256, bn0 = bx * 256;
    const int wm = wid >> 1, wn = wid & 1;

    f32x4 acc[4][8];
#pragma unroll
    for (int mi = 0; mi < 4; ++mi)
#pragma unroll
        for (int ni = 0; ni < 8; ++ni) acc[mi][ni] = (f32x4){0.f, 0.f, 0.f, 0.f};

    const float* aSrc = F + (size_t)(bm0 + wid * 32 + (l >> 1)) * K_DIM + (l & 1) * 32;
    const int arow = wid * 32 + (l >> 1);

#pragma unroll
    for (int kt = 0; kt < 4; ++kt) {
        float4 areg[8];
#pragma unroll
        for (int i = 0; i < 8; ++i)
            areg[i] = *(const float4*)(aSrc + kt * 64 + i * 4);

        if (kt > 0) __syncthreads();

#pragma unroll
        for (int j = 0; j < 4; ++j) {
            short8v hv;
            hv[0] = (short)f2bf(areg[2 * j].x);     hv[1] = (short)f2bf(areg[2 * j].y);
            hv[2] = (short)f2bf(areg[2 * j].z);     hv[3] = (short)f2bf(areg[2 * j].w);
            hv[4] = (short)f2bf(areg[2 * j + 1].x); hv[5] = (short)f2bf(areg[2 * j + 1].y);
            hv[6] = (short)f2bf(areg[2 * j + 1].z); hv[7] = (short)f2bf(areg[2 * j + 1].w);
            int c = (l & 1) * 4 + j, phys = c ^ (arow & 7);
            *(short8v*)&sA[arow * 64 + phys * 8] = hv;
        }
#pragma unroll
        for (int i = 0; i < 4; ++i) {
            int q = wid * 4 + i;
            const unsigned short* src = Ethi +
                (size_t)(bn0 + q * 8 + (l >> 3)) * K_DIM + kt * 64 +
                ((l & 7) ^ (l >> 3)) * 8;
            __builtin_amdgcn_global_load_lds(
                (const __attribute__((address_space(1))) unsigned int*)src,
                (__attribute__((address_space(3))) unsigned int*)&sB[q * 512],
                16, 0, 0);
        }
        __syncthreads();

#pragma unroll
        for (int s = 0; s < 2; ++s) {
            const int ch = s * 4 + (l >> 4);
            short8v af[4], bfv[8];
#pragma unroll
            for (int mi = 0; mi < 4; ++mi) {
                int r = wm * 64 + mi * 16 + (l & 15);
                af[mi] = *(const short8v*)&sA[r * 64 + (ch ^ (r & 7)) * 8];
            }
#pragma unroll
            for (int ni = 0; ni < 8; ++ni) {
                int c = wn * 128 + ni * 16 + (l & 15);
                bfv[ni] = *(const short8v*)&sB[c * 64 + (ch ^ (c & 7)) * 8];
            }
#pragma unroll
            for (int mi = 0; mi < 4; ++mi)
#pragma unroll
                for (int ni = 0; ni < 8; ++ni)
                    acc[mi][ni] = __builtin_amdgcn_mfma_f32_16x16x32_bf16(
                        af[mi], bfv[ni], acc[mi][ni], 0, 0, 0);
        }
    }

    float nv[8];
#pragma unroll
    for (int ni = 0; ni < 8; ++ni)
        nv[ni] = nrm[bn0 + wn * 128 + ni * 16 + (l & 15)];

#pragma unroll
    for (int mi = 0; mi < 4; ++mi)
#pragma unroll
        for (int rr = 0; rr < 4; ++rr) {
            unsigned long long k1 = ~0ull, k2 = ~0ull;
#pragma unroll
            for (int ni = 0; ni < 8; ++ni) {
                float d = fmaf(-2.f, acc[mi][ni][rr], nv[ni]);
                unsigned long long kk =
                    packKey(d, bn0 + wn * 128 + ni * 16 + (l & 15));
                if (kk < k1) { k2 = k1; k1 = kk; }
                else if (kk < k2) { k2 = kk; }
            }
#pragma unroll
            for (int st = 1; st < 16; st <<= 1) {
                unsigned long long o1 = __shfl_xor(k1, st, 64);
                unsigned long long o2 = __shfl_xor(k2, st, 64);
                unsigned long long hi = u64max(k1, o1);
                k1 = u64min(k1, o1);
                k2 = u64min(u64min(k2, o2), hi);
            }
            if ((l & 15) == 0) {
                int row = bm0 + wm * 64 + mi * 16 + (l >> 4) * 4 + rr;
                int g = bx * 2 + wn;
                keys2[(size_t)row * 64 + g * 2]     = k1;
                keys2[(size_t)row * 64 + g * 2 + 1] = k2;
            }
        }
}

// ---------------- rescore: LDS-staged, per-lane SERIAL chains --------------
// 1 row per wave, 4 waves/block. Candidates staged to LDS in batches of 8
// (coalesced wave-wide loads), then lane i runs the proven serial chain on
// staged row i. Group fallback: 16 chunks of 8 codes, 8 lanes chain each.
#define CSTRIDE 260   // floats; 1040B: 16B-aligned, banks 4i distinct for i<8
__global__ __launch_bounds__(256) void rescore_kernel(
    const float* __restrict__ F,
    const float* __restrict__ Et,
    const float* __restrict__ nrm,
    const float* __restrict__ maxnrm,
    const unsigned long long* __restrict__ keys2,
    float* __restrict__ q_out,
    float* __restrict__ diff_out,
    float* __restrict__ ind_out)
{
    __shared__ float sf[4][256];           // staged F row per wave
    __shared__ float sc[4][8][CSTRIDE];    // staged candidate rows per wave
    __shared__ float wpart[4];
    const int l = threadIdx.x & 63;
    const int wid = threadIdx.x >> 6;
    const float mxn = maxnrm[0];
    const int row = blockIdx.x * 4 + wid;   // 8192 blocks * 4 waves = 32768

    const unsigned long long* slots = keys2 + (size_t)row * 64;

    unsigned long long k = slots[l];
    float4 x4 = *(const float4*)&F[(size_t)row * K_DIM + l * 4];
    float dk = unpackDist(k);
    const int myc = (int)(k & 0xffffffffull);

    // stage F row (wave-local; compiler inserts lgkm waits before reads)
    *(float4*)&sf[wid][l * 4] = x4;

    float m = dk;
#pragma unroll
    for (int s = 1; s < 64; s <<= 1) m = fminf(m, __shfl_xor(m, s, 64));
    float nx = x4.x * x4.x;
    nx = fmaf(x4.y, x4.y, nx); nx = fmaf(x4.z, x4.z, nx); nx = fmaf(x4.w, x4.w, nx);
#pragma unroll
    for (int s = 1; s < 64; s <<= 1) nx += __shfl_xor(nx, s, 64);
    // window: rigorous 2*Delta = 0.03125*||x||*maxE; use 1.6x + slack
    const float thr = m + 0.05f * sqrtf(nx * mxn) + 0.25f;

    const unsigned long long cm = __ballot(dk <= thr);
    unsigned long long bestk = ~0ull;
    const float* fp = &sf[wid][0];

    // ---- in-window slots: batches of 8, staged to LDS, serial chains ----
    unsigned long long mrem = cm;
    while (mrem) {
        int nb = 0;       // wave-uniform batch fill count
        int mycand = -1;  // lane i's candidate id for batch slot i
#pragma unroll
        for (int i = 0; i < 8; ++i) {
            if (mrem) {
                int b = __ffsll(mrem) - 1;
                mrem &= mrem - 1;
                int c = __shfl(myc, b, 64);   // wave-uniform
                *(float4*)&sc[wid][i][l * 4] =
                    *(const float4*)&Et[(size_t)c * K_DIM + l * 4];
                if (l == i) mycand = c;
                ++nb;
            }
        }
        if (l < nb) {
            const float* cp = &sc[wid][0][0] + (size_t)l * CSTRIDE;
            float ex = serial_dot_lds(fp, cp);
            bestk = u64min(bestk, packKey(fmaf(-2.f, ex, nrm[mycand]), mycand));
        }
    }

    // ---- fallback: groups whose stored rank-2 is within thr -> all 128 ----
    unsigned long long fg = cm & 0xAAAAAAAAAAAAAAAAull;
    while (fg) {
        int b = __ffsll(fg) - 1;
        fg &= fg - 1;
        int g = b >> 1;
        for (int t = 0; t < 16; ++t) {
#pragma unroll
            for (int i = 0; i < 8; ++i) {
                int c = g * 128 + t * 8 + i;
                *(float4*)&sc[wid][i][l * 4] =
                    *(const float4*)&Et[(size_t)c * K_DIM + l * 4];
            }
            if (l < 8) {
                int c = g * 128 + t * 8 + l;
                const float* cp = &sc[wid][0][0] + (size_t)l * CSTRIDE;
                float ex = serial_dot_lds(fp, cp);
                bestk = u64min(bestk, packKey(fmaf(-2.f, ex, nrm[c]), c));
            }
        }
    }

#pragma unroll
    for (int s = 1; s < 64; s <<= 1)
        bestk = u64min(bestk, __shfl_xor(bestk, s, 64));

    const unsigned cstar = (unsigned)(bestk & 0xffffffffull);
    float4 e4 = *(const float4*)&Et[(size_t)cstar * K_DIM + l * 4];
    float d0 = e4.x - x4.x, d1 = e4.y - x4.y, d2 = e4.z - x4.z, d3 = e4.w - x4.w;
    float4 o = {x4.x + d0, x4.y + d1, x4.z + d2, x4.w + d3};
    *(float4*)&q_out[(size_t)row * K_DIM + l * 4] = o;
    float ldiff = 0.f;
    ldiff = fmaf(d0, d0, ldiff); ldiff = fmaf(d1, d1, ldiff);
    ldiff = fmaf(d2, d2, ldiff); ldiff = fmaf(d3, d3, ldiff);
    if (l == 0) ind_out[row] = (float)cstar;

#pragma unroll
    for (int s = 1; s < 64; s <<= 1) ldiff += __shfl_xor(ldiff, s, 64);
    if (l == 0) wpart[wid] = ldiff;
    __syncthreads();
    if (threadIdx.x == 0) {
        float t = 0.f;
#pragma unroll
        for (int i = 0; i < 4; ++i) t += wpart[i];
        atomicAdd(diff_out, t * (1.0f / ((float)M_ROWS * (float)K_DIM)));
    }
}

// ======================= LEGACY f32 fallback (round-1, proven) ==============
__global__ void norms_kernel(const float* __restrict__ E, float* __restrict__ norms) {
    int j = blockIdx.x * blockDim.x + threadIdx.x;
    if (j >= N_CODES) return;
    float s = 0.f;
    for (int d = 0; d < K_DIM; ++d) {
        float v = E[(size_t)d * N_CODES + j];
        s = fmaf(v, v, s);
    }
    norms[j] = s;
}

__global__ __launch_bounds__(256, 2) void gemm_argmin_kernel(
    const float* __restrict__ F, const float* __restrict__ E,
    const float* __restrict__ norms, unsigned long long* __restrict__ keys) {
    __shared__ float As[32][132];
    __shared__ float Bs[32][132];
    const int bx = blockIdx.x & 31, by = blockIdx.x >> 5;
    const int bm0 = by * 128, bn0 = bx * 128;
    const int tid = threadIdx.x;
    const int tx = tid & 15, ty = tid >> 4;
    float acc[8][8];
#pragma unroll
    for (int i = 0; i < 8; ++i)
#pragma unroll
        for (int j = 0; j < 8; ++j) acc[i][j] = 0.f;
    for (int kc = 0; kc < K_DIM; kc += 32) {
        float4 a_reg[4], b_reg[4];
#pragma unroll
        for (int i = 0; i < 4; ++i) {
            int idx = tid + i * 256;
            int m = idx >> 3, k4 = idx & 7;
            a_reg[i] = *(const float4*)&F[(size_t)(bm0 + m) * K_DIM + kc + k4 * 4];
            int kk = idx >> 5, n4 = idx & 31;
            b_reg[i] = *(const float4*)&E[(size_t)(kc + kk) * N_CODES + bn0 + n4 * 4];
        }
        __syncthreads();
#pragma unroll
        for (int i = 0; i < 4; ++i) {
            int idx = tid + i * 256;
            int m = idx >> 3, k4 = idx & 7;
            As[k4 * 4 + 0][m] = a_reg[i].x; As[k4 * 4 + 1][m] = a_reg[i].y;
            As[k4 * 4 + 2][m] = a_reg[i].z; As[k4 * 4 + 3][m] = a_reg[i].w;
            int kk = idx >> 5, n4 = idx & 31;
            *(float4*)&Bs[kk][n4 * 4] = b_reg[i];
        }
        __syncthreads();
#pragma unroll
        for (int k = 0; k < 32; ++k) {
            float a[8], b[8];
            *(float4*)&a[0] = *(const float4*)&As[k][ty * 8];
            *(float4*)&a[4] = *(const float4*)&As[k][ty * 8 + 4];
            *(float4*)&b[0] = *(const float4*)&Bs[k][tx * 8];
            *(float4*)&b[4] = *(const float4*)&Bs[k][tx * 8 + 4];
#pragma unroll
            for (int i = 0; i < 8; ++i)
#pragma unroll
                for (int j = 0; j < 8; ++j) acc[i][j] = fmaf(a[i], b[j], acc[i][j]);
        }
    }
    float nrm8[8];
#pragma unroll
    for (int j = 0; j < 8; ++j) nrm8[j] = norms[bn0 + tx * 8 + j];
#pragma unroll
    for (int i = 0; i < 8; ++i) {
        float best = INFINITY; int bestj = 0;
#pragma unroll
        for (int j = 0; j < 8; ++j) {
            float d = fmaf(-2.f, acc[i][j], nrm8[j]);
            if (d < best) { best = d; bestj = bn0 + tx * 8 + j; }
        }
        unsigned long long key = packKey(best, bestj);
#pragma unroll
        for (int s = 1; s < 16; s <<= 1) {
            unsigned long long o = __shfl_xor(key, s, 64);
            if (o < key) key = o;
        }
        if (tx == 0) atomicMin(&keys[bm0 + ty * 8 + i], key);
    }
}

__global__ void gather_legacy_kernel(
    const float* __restrict__ F, const float* __restrict__ E,
    const unsigned long long* __restrict__ keys,
    float* __restrict__ q_out, float* __restrict__ diff_out,
    float* __restrict__ ind_out) {
    const int lane = threadIdx.x & 63;
    const int wave = (blockIdx.x * (blockDim.x >> 6)) + (threadIdx.x >> 6);
    const int nwaves = gridDim.x * (blockDim.x >> 6);
    float dsum = 0.f;
    for (int row = wave; row < M_ROWS; row += nwaves) {
        int ind = (int)(keys[row] & 0xFFFFFFFFull);
        if (lane == 0) ind_out[row] = (float)ind;
#pragma unroll
        for (int t = 0; t < 4; ++t) {
            int d = lane + t * 64;
            float x = F[(size_t)row * K_DIM + d];
            float q = E[(size_t)d * N_CODES + ind];
            float delta = q - x;
            q_out[(size_t)row * K_DIM + d] = x + delta;
            dsum = fmaf(delta, delta, dsum);
        }
    }
#pragma unroll
    for (int s = 32; s >= 1; s >>= 1) dsum += __shfl_xor(dsum, s, 64);
    if (lane == 0)
        atomicAdd(diff_out, dsum * (1.0f / ((float)M_ROWS * (float)K_DIM)));
}

// ============================== launch ==============================
extern "C" void kernel_launch(void* const* d_in, const int* in_sizes, int n_in,
                              void* d_out, int out_size, void* d_ws, size_t ws_size,
                              hipStream_t stream) {
    const float* F = (const float*)d_in[0];
    const float* E = (const float*)d_in[1];

    float* q_out = (float*)d_out;
    float* diff_out = q_out + (size_t)M_ROWS * K_DIM;
    float* ind_out = diff_out + 1;

    const size_t off_nrm  = 0;                       // 16 KB
    const size_t off_mx   = 16384;                   // 4 B
    const size_t off_Et   = 32768;                   // 4 MB
    const size_t off_Ethi = off_Et + (size_t)N_CODES * K_DIM * 4;    // 2 MB
    const size_t off_k2   = off_Ethi + (size_t)N_CODES * K_DIM * 2;  // 16 MB
    const size_t NEED     = off_k2 + (size_t)M_ROWS * 64 * 8;

    if (ws_size >= NEED) {
        float* nrm = (float*)((char*)d_ws + off_nrm);
        float* maxnrm = (float*)((char*)d_ws + off_mx);
        float* Et = (float*)((char*)d_ws + off_Et);
        unsigned short* Ethi = (unsigned short*)((char*)d_ws + off_Ethi);
        unsigned long long* keys2 = (unsigned long long*)((char*)d_ws + off_k2);

        hipMemsetAsync(maxnrm, 0, 4, stream);
        hipMemsetAsync(diff_out, 0, 4, stream);

        transpose_kernel<<<256, 256, 0, stream>>>(E, Et, Ethi);
        nrm_et_kernel<<<1024, 256, 0, stream>>>(Et, nrm, maxnrm);
        gemm_top2_kernel<<<2048, 512, 0, stream>>>(F, Ethi, nrm, keys2);
        rescore_kernel<<<8192, 256, 0, stream>>>(F, Et, nrm, maxnrm, keys2,
                                                 q_out, diff_out, ind_out);
    } else {
        float* norms = (float*)d_ws;
        unsigned long long* keys = (unsigned long long*)((char*)d_ws + 16384);
        hipMemsetAsync(keys, 0xFF, (size_t)M_ROWS * 8, stream);
        hipMemsetAsync(diff_out, 0, 4, stream);
        norms_kernel<<<N_CODES / 256, 256, 0, stream>>>(E, norms);
        gemm_argmin_kernel<<<(M_ROWS / 128) * (N_CODES / 128), 256, 0, stream>>>(F, E, norms, keys);
        gather_legacy_kernel<<<1024, 256, 0, stream>>>(F, E, keys, q_out, diff_out, ind_out);
    }
}